// Round 1
// 1611.706 us; speedup vs baseline: 1.0631x; 1.0631x over previous
//
#include <hip/hip_runtime.h>
#include <hip/hip_bf16.h>
#include <cstdint>
#include <cstddef>

#define TILE_BM 64
#define TILE_BN 64
#define TILE_BK 32
#define SCAN_CHUNK 1024

// ---------------------------------------------------------------------------
// Encoder: out[r][c] = sum_k X[r][k]*W[c][k] + bias[c] + emb[ids[r]][c]
// M x K  @  (64 x K)^T  -> M x 64.   Block = 256 thr, tile 64x64, 4x4/thread.
// ---------------------------------------------------------------------------
__global__ __launch_bounds__(256)
void encoder_kernel(const float* __restrict__ X, int K,
                    const float* __restrict__ W,
                    const float* __restrict__ bias,
                    const int* __restrict__ ids,
                    const float* __restrict__ emb,
                    float* __restrict__ out, int M)
{
    __shared__ float As[TILE_BK][TILE_BM + 4];
    __shared__ float Bs[TILE_BK][TILE_BN + 4];
    const int tid  = threadIdx.x;
    const int row0 = blockIdx.x * TILE_BM;
    const int tr   = tid >> 4;   // 0..15 -> rows tr*4..tr*4+3
    const int tc   = tid & 15;   // 0..15 -> cols tc*4..tc*4+3

    float acc[4][4];
#pragma unroll
    for (int i = 0; i < 4; i++)
#pragma unroll
        for (int j = 0; j < 4; j++) acc[i][j] = 0.f;

    for (int k0 = 0; k0 < K; k0 += TILE_BK) {
        // A tile: 64 rows x 32 k  (512 float4, 2 per thread)
#pragma unroll
        for (int i = 0; i < 2; i++) {
            int idx = tid + i * 256;
            int r = idx >> 3;
            int j = idx & 7;
            int gr = row0 + r;
            float4 v = make_float4(0.f, 0.f, 0.f, 0.f);
            if (gr < M) v = *(const float4*)&X[(size_t)gr * K + k0 + j * 4];
            As[j * 4 + 0][r] = v.x; As[j * 4 + 1][r] = v.y;
            As[j * 4 + 2][r] = v.z; As[j * 4 + 3][r] = v.w;
        }
        // B tile: 64 out-channels x 32 k
#pragma unroll
        for (int i = 0; i < 2; i++) {
            int idx = tid + i * 256;
            int c = idx >> 3;
            int j = idx & 7;
            float4 v = *(const float4*)&W[(size_t)c * K + k0 + j * 4];
            Bs[j * 4 + 0][c] = v.x; Bs[j * 4 + 1][c] = v.y;
            Bs[j * 4 + 2][c] = v.z; Bs[j * 4 + 3][c] = v.w;
        }
        __syncthreads();
#pragma unroll
        for (int kk = 0; kk < TILE_BK; kk++) {
            float4 av = *(const float4*)&As[kk][tr * 4];
            float4 bv = *(const float4*)&Bs[kk][tc * 4];
            float a_[4] = {av.x, av.y, av.z, av.w};
            float b_[4] = {bv.x, bv.y, bv.z, bv.w};
#pragma unroll
            for (int i = 0; i < 4; i++)
#pragma unroll
                for (int j = 0; j < 4; j++) acc[i][j] += a_[i] * b_[j];
        }
        __syncthreads();
    }

    float4 bv = *(const float4*)&bias[tc * 4];
#pragma unroll
    for (int i = 0; i < 4; i++) {
        int r = row0 + tr * 4 + i;
        if (r >= M) continue;
        int id = ids[r];
        float4 ev = *(const float4*)&emb[(size_t)id * 64 + tc * 4];
        float4 o;
        o.x = acc[i][0] + bv.x + ev.x;
        o.y = acc[i][1] + bv.y + ev.y;
        o.z = acc[i][2] + bv.z + ev.z;
        o.w = acc[i][3] + bv.w + ev.w;
        *(float4*)&out[(size_t)r * 64 + tc * 4] = o;
    }
}

// ---------------------------------------------------------------------------
// SAGE linear: out = A0 @ W0^T + A1 @ W1^T + bias  (optional ReLU)
// A0,A1: M x 64.  W0,W1: 64 x 64.
// ---------------------------------------------------------------------------
__global__ __launch_bounds__(256)
void sage_linear_kernel(const float* __restrict__ A0, const float* __restrict__ W0,
                        const float* __restrict__ A1, const float* __restrict__ W1,
                        const float* __restrict__ bias, float* __restrict__ out,
                        int M, int relu)
{
    __shared__ float As[TILE_BK][TILE_BM + 4];
    __shared__ float Bs[TILE_BK][TILE_BN + 4];
    const int tid  = threadIdx.x;
    const int row0 = blockIdx.x * TILE_BM;
    const int tr   = tid >> 4;
    const int tc   = tid & 15;

    float acc[4][4];
#pragma unroll
    for (int i = 0; i < 4; i++)
#pragma unroll
        for (int j = 0; j < 4; j++) acc[i][j] = 0.f;

    for (int phase = 0; phase < 2; phase++) {
        const float* A = phase ? A1 : A0;
        const float* W = phase ? W1 : W0;
        for (int k0 = 0; k0 < 64; k0 += TILE_BK) {
#pragma unroll
            for (int i = 0; i < 2; i++) {
                int idx = tid + i * 256;
                int r = idx >> 3;
                int j = idx & 7;
                int gr = row0 + r;
                float4 v = make_float4(0.f, 0.f, 0.f, 0.f);
                if (gr < M) v = *(const float4*)&A[(size_t)gr * 64 + k0 + j * 4];
                As[j * 4 + 0][r] = v.x; As[j * 4 + 1][r] = v.y;
                As[j * 4 + 2][r] = v.z; As[j * 4 + 3][r] = v.w;
            }
#pragma unroll
            for (int i = 0; i < 2; i++) {
                int idx = tid + i * 256;
                int c = idx >> 3;
                int j = idx & 7;
                float4 v = *(const float4*)&W[(size_t)c * 64 + k0 + j * 4];
                Bs[j * 4 + 0][c] = v.x; Bs[j * 4 + 1][c] = v.y;
                Bs[j * 4 + 2][c] = v.z; Bs[j * 4 + 3][c] = v.w;
            }
            __syncthreads();
#pragma unroll
            for (int kk = 0; kk < TILE_BK; kk++) {
                float4 av = *(const float4*)&As[kk][tr * 4];
                float4 bv = *(const float4*)&Bs[kk][tc * 4];
                float a_[4] = {av.x, av.y, av.z, av.w};
                float b_[4] = {bv.x, bv.y, bv.z, bv.w};
#pragma unroll
                for (int i = 0; i < 4; i++)
#pragma unroll
                    for (int j = 0; j < 4; j++) acc[i][j] += a_[i] * b_[j];
            }
            __syncthreads();
        }
    }

    float4 bv = *(const float4*)&bias[tc * 4];
#pragma unroll
    for (int i = 0; i < 4; i++) {
        int r = row0 + tr * 4 + i;
        if (r >= M) continue;
        float4 o;
        o.x = acc[i][0] + bv.x;
        o.y = acc[i][1] + bv.y;
        o.z = acc[i][2] + bv.z;
        o.w = acc[i][3] + bv.w;
        if (relu) {
            o.x = fmaxf(o.x, 0.f); o.y = fmaxf(o.y, 0.f);
            o.z = fmaxf(o.z, 0.f); o.w = fmaxf(o.w, 0.f);
        }
        *(float4*)&out[(size_t)r * 64 + tc * 4] = o;
    }
}

// ---------------------------------------------------------------------------
// Degree count (int)
// ---------------------------------------------------------------------------
__global__ void deg_int_kernel(const int* __restrict__ src, const int* __restrict__ dst,
                               int* __restrict__ deg_t, int* __restrict__ deg_m, int E)
{
    int e = blockIdx.x * 256 + threadIdx.x;
    if (e < E) {
        atomicAdd(&deg_t[src[e]], 1);
        atomicAdd(&deg_m[dst[e]], 1);
    }
}

// ---------------------------------------------------------------------------
// Two-level exclusive scan over int array (n <= 1024*1024).
// scan1: per-1024-chunk sums.  scan2: single-block exclusive scan of chunk
// sums (nb <= 1024).  scan3: local rescan + add chunk offset; writes off & cur.
// ---------------------------------------------------------------------------
__global__ __launch_bounds__(256)
void scan1_kernel(const int* __restrict__ in, int* __restrict__ bsum, int n)
{
    __shared__ int lds[256];
    const int base = blockIdx.x * SCAN_CHUNK;
    const int t = threadIdx.x;
    int s = 0;
#pragma unroll
    for (int i = 0; i < 4; i++) {
        int idx = base + t * 4 + i;
        if (idx < n) s += in[idx];
    }
    lds[t] = s;
    __syncthreads();
    for (int st = 128; st > 0; st >>= 1) {
        if (t < st) lds[t] += lds[t + st];
        __syncthreads();
    }
    if (t == 0) bsum[blockIdx.x] = lds[0];
}

__global__ __launch_bounds__(1024)
void scan2_kernel(int* __restrict__ bsum, int nb)
{
    __shared__ int lds[1024];
    const int t = threadIdx.x;
    int v = (t < nb) ? bsum[t] : 0;
    lds[t] = v;
    __syncthreads();
    int incl = v;
    for (int st = 1; st < 1024; st <<= 1) {
        int add = (t >= st) ? lds[t - st] : 0;
        __syncthreads();
        incl += add;
        lds[t] = incl;
        __syncthreads();
    }
    if (t < nb) bsum[t] = incl - v;   // exclusive
}

__global__ __launch_bounds__(256)
void scan3_kernel(const int* __restrict__ in, const int* __restrict__ bsum,
                  int* __restrict__ off, int* __restrict__ cur, int n)
{
    __shared__ int lds[256];
    const int base = blockIdx.x * SCAN_CHUNK;
    const int t = threadIdx.x;
    int v[4];
    int s = 0;
#pragma unroll
    for (int i = 0; i < 4; i++) {
        int idx = base + t * 4 + i;
        v[i] = (idx < n) ? in[idx] : 0;
        s += v[i];
    }
    lds[t] = s;
    __syncthreads();
    int incl = s;
    for (int st = 1; st < 256; st <<= 1) {
        int add = (t >= st) ? lds[t - st] : 0;
        __syncthreads();
        incl += add;
        lds[t] = incl;
        __syncthreads();
    }
    int run = incl - s + bsum[blockIdx.x];
#pragma unroll
    for (int i = 0; i < 4; i++) {
        int idx = base + t * 4 + i;
        if (idx < n) {
            off[idx] = run;
            cur[idx] = run;
            run += v[i];
        }
    }
}

// ---------------------------------------------------------------------------
// CSR fill: place each edge into both direction's column arrays.
// Order within a row is arbitrary (fp32 sum order differs only by rounding).
// ---------------------------------------------------------------------------
__global__ void csr_fill_kernel(const int* __restrict__ src, const int* __restrict__ dst,
                                int* __restrict__ curT, int* __restrict__ curM,
                                int* __restrict__ colT, int* __restrict__ colM, int E)
{
    int e = blockIdx.x * 256 + threadIdx.x;
    if (e < E) {
        int s = src[e];
        int d = dst[e];
        int pt = atomicAdd(&curT[s], 1);
        colT[pt] = d;
        int pm = atomicAdd(&curM[d], 1);
        colM[pm] = s;
    }
}

// ---------------------------------------------------------------------------
// CSR gather-mean: out[r][c] = (1/max(deg,1)) * sum_i feat[col[off[r]+i]][c]
// One wave (64 lanes) per row -> col[] loads are wave-uniform (broadcast),
// feat row reads are 256B coalesced, stores are plain (no atomics, no memset).
// ---------------------------------------------------------------------------
__global__ __launch_bounds__(256)
void agg_gather_kernel(const float* __restrict__ feat, const int* __restrict__ off,
                       const int* __restrict__ deg, const int* __restrict__ col,
                       float* __restrict__ out, int M)
{
    int gid = blockIdx.x * 256 + threadIdx.x;
    int r = gid >> 6;
    int c = gid & 63;
    if (r >= M) return;
    int o = off[r];
    int d = deg[r];
    float acc0 = 0.f, acc1 = 0.f;
    int i = 0;
    for (; i + 2 <= d; i += 2) {
        int c0 = col[o + i];
        int c1 = col[o + i + 1];
        acc0 += feat[(size_t)c0 * 64 + c];
        acc1 += feat[(size_t)c1 * 64 + c];
    }
    if (i < d) acc0 += feat[(size_t)col[o + i] * 64 + c];
    float inv = 1.f / (float)max(d, 1);
    out[(size_t)r * 64 + c] = (acc0 + acc1) * inv;
}

// ---------------------------------------------------------------------------
// Row gather: out[r] = src[ids[r]]   (rows of 64 floats, 16 lanes/row)
// ---------------------------------------------------------------------------
__global__ void gather_rows_kernel(const float* __restrict__ src, const int* __restrict__ ids,
                                   float* __restrict__ out, int M)
{
    int gid = blockIdx.x * 256 + threadIdx.x;
    int r = gid >> 4;
    int j = gid & 15;
    if (r < M) {
        *(float4*)&out[(size_t)r * 64 + j * 4] =
            *(const float4*)&src[(size_t)ids[r] * 64 + j * 4];
    }
}

// ---------------------------------------------------------------------------
// Classifier: out[g] = dot(xt[es[g]], xm[ed[g]])   (16 lanes/edge, float4)
// ---------------------------------------------------------------------------
__global__ __launch_bounds__(256)
void classify_kernel(const float* __restrict__ xt, const float* __restrict__ xm,
                     const int* __restrict__ es, const int* __restrict__ ed,
                     float* __restrict__ out, int EL)
{
    int gid = blockIdx.x * 256 + threadIdx.x;
    int g = gid >> 4;
    int j = gid & 15;
    if (g < EL) {
        int s = es[g];
        int d = ed[g];
        float4 a = *(const float4*)&xt[(size_t)s * 64 + j * 4];
        float4 b = *(const float4*)&xm[(size_t)d * 64 + j * 4];
        float v = a.x * b.x + a.y * b.y + a.z * b.z + a.w * b.w;
        v += __shfl_down(v, 8, 16);
        v += __shfl_down(v, 4, 16);
        v += __shfl_down(v, 2, 16);
        v += __shfl_down(v, 1, 16);
        if (j == 0) out[g] = v;
    }
}

// ---------------------------------------------------------------------------
extern "C" void kernel_launch(void* const* d_in, const int* in_sizes, int n_in,
                              void* d_out, int out_size, void* d_ws, size_t ws_size,
                              hipStream_t stream)
{
    const float* x_thesis  = (const float*)d_in[0];
    const int*   thesis_id = (const int*)d_in[1];
    const int*   mentor_id = (const int*)d_in[2];
    const int*   edge_src  = (const int*)d_in[3];
    const int*   edge_dst  = (const int*)d_in[4];
    const int*   el_src    = (const int*)d_in[5];
    const int*   el_dst    = (const int*)d_in[6];
    const float* lin_W     = (const float*)d_in[7];
    const float* lin_b     = (const float*)d_in[8];
    const float* emb_t     = (const float*)d_in[9];
    const float* emb_m     = (const float*)d_in[10];
    const float* Wl_tm0    = (const float*)d_in[11];
    const float* Wr_tm0    = (const float*)d_in[12];
    const float* b_tm0     = (const float*)d_in[13];
    const float* Wl_mt0    = (const float*)d_in[14];
    const float* Wr_mt0    = (const float*)d_in[15];
    const float* b_mt0     = (const float*)d_in[16];
    const float* Wl_tm1    = (const float*)d_in[17];
    const float* Wr_tm1    = (const float*)d_in[18];
    const float* b_tm1     = (const float*)d_in[19];
    const float* Wl_mt1    = (const float*)d_in[20];
    const float* Wr_mt1    = (const float*)d_in[21];
    const float* b_mt1     = (const float*)d_in[22];

    const int NT = in_sizes[1];
    const int NM = in_sizes[2];
    const int E  = in_sizes[3];
    const int EL = in_sizes[5];
    const int FT = in_sizes[0] / NT;

    // workspace layout (256B aligned)
    char* ws = (char*)d_ws;
    size_t off = 0;
    auto alloc = [&](size_t bytes) -> void* {
        void* p = ws + off;
        off += (bytes + 255) & ~(size_t)255;
        return p;
    };
    float* xt_a  = (float*)alloc((size_t)NT * 64 * 4);
    float* xt_b  = (float*)alloc((size_t)NT * 64 * 4);
    float* agg_t = (float*)alloc((size_t)NT * 64 * 4);
    float* xm_a  = (float*)alloc((size_t)NM * 64 * 4);
    float* xm_b  = (float*)alloc((size_t)NM * 64 * 4);
    float* agg_m = (float*)alloc((size_t)NM * 64 * 4);
    int*   deg_t = (int*)alloc((size_t)NT * 4);
    int*   deg_m = (int*)alloc((size_t)NM * 4);
    int*   off_t = (int*)alloc((size_t)NT * 4);
    int*   cur_t = (int*)alloc((size_t)NT * 4);
    int*   off_m = (int*)alloc((size_t)NM * 4);
    int*   cur_m = (int*)alloc((size_t)NM * 4);
    int*   col_t = (int*)alloc((size_t)E * 4);   // mentor ids grouped by thesis
    int*   col_m = (int*)alloc((size_t)E * 4);   // thesis ids grouped by mentor
    int*   bsum_t = (int*)alloc((size_t)1024 * 4);
    int*   bsum_m = (int*)alloc((size_t)1024 * 4);
    (void)ws_size; (void)n_in; (void)out_size;

    const int nbT = (NT + SCAN_CHUNK - 1) / SCAN_CHUNK;
    const int nbM = (NM + SCAN_CHUNK - 1) / SCAN_CHUNK;

    // ---- CSR build (amortized over 4 aggregations) ----
    hipMemsetAsync(deg_t, 0, (size_t)NT * 4, stream);
    hipMemsetAsync(deg_m, 0, (size_t)NM * 4, stream);
    deg_int_kernel<<<(E + 255) / 256, 256, 0, stream>>>(edge_src, edge_dst, deg_t, deg_m, E);
    scan1_kernel<<<nbT, 256, 0, stream>>>(deg_t, bsum_t, NT);
    scan2_kernel<<<1, 1024, 0, stream>>>(bsum_t, nbT);
    scan3_kernel<<<nbT, 256, 0, stream>>>(deg_t, bsum_t, off_t, cur_t, NT);
    scan1_kernel<<<nbM, 256, 0, stream>>>(deg_m, bsum_m, NM);
    scan2_kernel<<<1, 1024, 0, stream>>>(bsum_m, nbM);
    scan3_kernel<<<nbM, 256, 0, stream>>>(deg_m, bsum_m, off_m, cur_m, NM);
    csr_fill_kernel<<<(E + 255) / 256, 256, 0, stream>>>(edge_src, edge_dst,
                                                         cur_t, cur_m, col_t, col_m, E);

    // ---- node encoders ----
    encoder_kernel<<<(NT + 63) / 64, 256, 0, stream>>>(x_thesis, FT, lin_W, lin_b,
                                                       thesis_id, emb_t, xt_a, NT);
    gather_rows_kernel<<<(NM * 16 + 255) / 256, 256, 0, stream>>>(emb_m, mentor_id, xm_a, NM);

    const int gridAggT = (int)(((size_t)NT * 64 + 255) / 256);
    const int gridAggM = (int)(((size_t)NM * 64 + 255) / 256);

    // ---- layer 0 (ReLU) ----
    agg_gather_kernel<<<gridAggM, 256, 0, stream>>>(xt_a, off_m, deg_m, col_m, agg_m, NM);
    agg_gather_kernel<<<gridAggT, 256, 0, stream>>>(xm_a, off_t, deg_t, col_t, agg_t, NT);
    sage_linear_kernel<<<(NM + 63) / 64, 256, 0, stream>>>(agg_m, Wl_tm0, xm_a, Wr_tm0,
                                                           b_tm0, xm_b, NM, 1);
    sage_linear_kernel<<<(NT + 63) / 64, 256, 0, stream>>>(agg_t, Wl_mt0, xt_a, Wr_mt0,
                                                           b_mt0, xt_b, NT, 1);

    // ---- layer 1 (no ReLU) ----
    agg_gather_kernel<<<gridAggM, 256, 0, stream>>>(xt_b, off_m, deg_m, col_m, agg_m, NM);
    agg_gather_kernel<<<gridAggT, 256, 0, stream>>>(xm_b, off_t, deg_t, col_t, agg_t, NT);
    sage_linear_kernel<<<(NM + 63) / 64, 256, 0, stream>>>(agg_m, Wl_tm1, xm_b, Wr_tm1,
                                                           b_tm1, xm_a, NM, 0);
    sage_linear_kernel<<<(NT + 63) / 64, 256, 0, stream>>>(agg_t, Wl_mt1, xt_b, Wr_mt1,
                                                           b_mt1, xt_a, NT, 0);

    // ---- edge classifier ----
    classify_kernel<<<(int)(((size_t)EL * 16 + 255) / 256), 256, 0, stream>>>(
        xt_a, xm_a, el_src, el_dst, (float*)d_out, EL);
}